// Round 6
// baseline (592.564 us; speedup 1.0000x reference)
//
#include <hip/hip_runtime.h>

typedef unsigned short u16;
typedef unsigned int u32;
typedef __attribute__((ext_vector_type(8))) short short8;
typedef __attribute__((ext_vector_type(4))) float f32x4;

#define NF 65536
#define KDIM 1024
#define NDIM 1024
#define NE 8
#define BM 128
#define BN 128
#define MAX_MT (NF / BM + NE)   // 520 upper bound on total m-tiles
#define GEMM_GRID (MAX_MT * 8)  // 4160, divisible by 8 (XCD swizzle valid)
#define TILE_B 16384            // one 128x64 bf16 tile = LDS image bytes
#define SORT_BLOCKS 64

#define AS1 __attribute__((address_space(1)))
#define AS3 __attribute__((address_space(3)))

__device__ __forceinline__ u16 f2bf(float f) {
  u32 u = __float_as_uint(f);
  u += 0x7FFF + ((u >> 16) & 1);  // RNE (no NaN in this data)
  return (u16)(u >> 16);
}

// 3-bit slot swizzle
__device__ __forceinline__ int swz8(int r) {
  return (r & 7) ^ ((r >> 3) & 7);
}
__device__ __forceinline__ int swz_slot(int r) { return swz8(r) << 4; }

__device__ __forceinline__ void cp16(void* l, const void* g) {
  __builtin_amdgcn_global_load_lds((const AS1 unsigned int*)g,
                                   (AS3 unsigned int*)l, 16, 0, 0);
}

// pack two f32 -> two bf16 (RNE) in one VALU op
__device__ __forceinline__ u32 cvtpk(float a, float b) {
  u32 r;
  asm("v_cvt_pk_bf16_f32 %0, %1, %2" : "=v"(r) : "v"(a), "v"(b));
  return r;
}

// ---------- deterministic (atomic-free) counting sort ----------
__global__ void k_cnt(const int* __restrict__ ids, int* __restrict__ gcnt) {
  __shared__ int wc[16][NE];
  int b = blockIdx.x, t = threadIdx.x;
  int w = t >> 6, lane = t & 63;
  if (t < 16 * NE) ((int*)wc)[t] = 0;
  __syncthreads();
  for (int s = 0; s < 4; ++s) {
    int i = (b << 10) + (s << 8) + t;
    int e = ids[i];
#pragma unroll
    for (int ee = 0; ee < NE; ++ee) {
      unsigned long long mask = __ballot(e == ee);
      if (lane == 0) wc[(s << 2) + w][ee] = (int)__popcll(mask);
    }
  }
  __syncthreads();
  if (t < NE) {
    int sum = 0;
#pragma unroll
    for (int j = 0; j < 16; ++j) sum += wc[j][t];
    gcnt[b * NE + t] = sum;
  }
}

__global__ void k_excl(const int* __restrict__ gcnt, int* __restrict__ counts,
                       int* __restrict__ offsets, int* __restrict__ tile_base,
                       int* __restrict__ base) {
  __shared__ int tot[NE], offs[NE];
  int t = threadIdx.x;
  if (t < NE) {
    int s = 0;
    for (int b = 0; b < SORT_BLOCKS; ++b) s += gcnt[b * NE + t];
    tot[t] = s;
    counts[t] = s;
  }
  __syncthreads();
  if (t == 0) {
    int run = 0, tb = 0;
    tile_base[0] = 0;
    for (int e = 0; e < NE; ++e) {
      offsets[e] = run;
      offs[e] = run;
      run += tot[e];
      tb += (tot[e] + BM - 1) / BM;
      tile_base[e + 1] = tb;
    }
  }
  __syncthreads();
  if (t < NE) {
    int run = offs[t];
    for (int b = 0; b < SORT_BLOCKS; ++b) {
      base[b * NE + t] = run;
      run += gcnt[b * NE + t];
    }
  }
}

__global__ void k_place(const int* __restrict__ ids, const int* __restrict__ base,
                        int* __restrict__ perm) {
  __shared__ int wc[16][NE], wsc[16][NE];
  int b = blockIdx.x, t = threadIdx.x;
  int w = t >> 6, lane = t & 63;
  for (int s = 0; s < 4; ++s) {
    int i = (b << 10) + (s << 8) + t;
    int e = ids[i];
#pragma unroll
    for (int ee = 0; ee < NE; ++ee) {
      unsigned long long mask = __ballot(e == ee);
      if (lane == 0) wc[(s << 2) + w][ee] = (int)__popcll(mask);
    }
  }
  __syncthreads();
  if (t < NE) {
    int run = 0;
#pragma unroll
    for (int j = 0; j < 16; ++j) {
      wsc[j][t] = run;
      run += wc[j][t];
    }
  }
  __syncthreads();
  for (int s = 0; s < 4; ++s) {
    int i = (b << 10) + (s << 8) + t;
    int e = ids[i];
#pragma unroll
    for (int ee = 0; ee < NE; ++ee) {
      unsigned long long mask = __ballot(e == ee);
      if (e == ee) {
        int rank = (int)__popcll(mask & ((1ull << lane) - 1ull));
        perm[base[b * NE + e] + wsc[(s << 2) + w][e] + rank] = i;
      }
    }
  }
}

// W[e][k][n] fp32 -> bf16 tiles [e][nt][kt][swizzled 128x64 image]
__global__ void k_wconv2(const float* __restrict__ W, u16* __restrict__ Wt) {
  int b = blockIdx.x;  // 8*8*16 = 1024 : b = (e*8+nt)*16+kt
  int e = b >> 7, nt = (b >> 4) & 7, kt = b & 15;
  int tid = threadIdx.x;
  const float* We = W + ((size_t)e << 20);
  char* dst = (char*)Wt + (size_t)b * TILE_B;
#pragma unroll
  for (int i = 0; i < 4; ++i) {
    int o = (i << 12) + (tid << 4);
    int r = o >> 7;
    int s = ((o >> 4) & 7) ^ swz8(r);
    int n = (nt << 7) + r;
    int k = (kt << 6) + (s << 3);
    u32 p[4];
#pragma unroll
    for (int j = 0; j < 4; ++j) {
      u32 lo = f2bf(We[(size_t)(k + 2 * j) * NDIM + n]);
      u32 hi = f2bf(We[(size_t)(k + 2 * j + 1) * NDIM + n]);
      p[j] = lo | (hi << 16);
    }
    *(uint4*)(dst + o) = make_uint4(p[0], p[1], p[2], p[3]);
  }
}

// ---------- fused grouped GEMM, A direct global->VGPR ----------
// A-fragments are lane-private: load straight from global (two float4 per
// (m,kk)), convert with v_cvt_pk_bf16_f32. Only B lives in LDS (dbuf 2x16KB,
// one barrier per K-step). Removes 96KB/blk-Kstep of LDS traffic vs R5.
__global__ __launch_bounds__(256, 3) void k_gemm_fused(
    const float* __restrict__ A, const u16* __restrict__ Wt,
    const float* __restrict__ bias, const int* __restrict__ perm,
    const int* __restrict__ offsets, const int* __restrict__ counts,
    const int* __restrict__ tile_base, float* __restrict__ out) {
  int bid = blockIdx.x;
  const int cpx = GEMM_GRID >> 3;
  int l = (bid & 7) * cpx + (bid >> 3);  // XCD swizzle
  int mt = l >> 3, nt = l & 7;           // n fastest: A-panel L2 reuse
  if (mt >= tile_base[NE]) return;
  int e = 0;
#pragma unroll
  for (int ee = 0; ee < NE - 1; ++ee)
    if (mt >= tile_base[ee + 1]) e = ee + 1;
  int mloc = mt - tile_base[e];
  int row_base = offsets[e] + (mloc << 7);
  int rim = counts[e] - (mloc << 7);
  rim = rim < BM ? rim : BM;
  int n0 = nt << 7;

  __shared__ __align__(16) char ldsB[2][TILE_B];  // 32 KB, double-buffered

  int tid = threadIdx.x;
  int lane = tid & 63, wid = tid >> 6;
  int wr = wid >> 1, wc = wid & 1;
  int l15 = lane & 15;
  int q4 = lane >> 4;
  int lk2 = q4 << 4;

  // ---- A row pointers (lane-private frag rows), k-offset q4*8 floats
  const float* ap[4];
#pragma unroll
  for (int m = 0; m < 4; ++m) {
    int r = (wr << 6) + (m << 4) + l15;
    int rr = r < rim ? r : rim - 1;  // dup row for pad (dead rows discarded)
    int g = perm[row_base + rr];
    ap[m] = A + (size_t)g * KDIM + (q4 << 3);
  }

  // ---- B staging: Wt tile byte order == LDS image; 4 issues x 4KB strided.
  const char* srcB = (const char*)Wt + (size_t)(((e << 3) + nt) << 4) * TILE_B;
  int toff = tid << 4;

  // ---- B frag read addresses (kk -> ^64)
  int br_addr[4];
#pragma unroll
  for (int n = 0; n < 4; ++n) {
    int r = (wc << 6) + (n << 4) + l15;
    br_addr[n] = (r << 7) + (lk2 ^ swz_slot(r));
  }

  f32x4 acc[4][4];
#pragma unroll
  for (int m = 0; m < 4; ++m)
#pragma unroll
    for (int n = 0; n < 4; ++n) acc[m][n] = f32x4{0.f, 0.f, 0.f, 0.f};

  // prologue: stage B(0) into buf0
#pragma unroll
  for (int j = 0; j < 4; ++j) cp16(&ldsB[0][0] + toff + (j << 12), srcB + toff + (j << 12));

#pragma unroll 1
  for (int kt = 0; kt < KDIM / 64; ++kt) {
    // issue B(t+1) into the other buffer (no conflict with readers of buf[t&1])
    if (kt < KDIM / 64 - 1) {
      const char* gb = srcB + ((size_t)(kt + 1) << 14);
      char* lb = &ldsB[(kt + 1) & 1][0];
#pragma unroll
      for (int j = 0; j < 4; ++j) cp16(lb + toff + (j << 12), gb + toff + (j << 12));
    }
    // A(t) loads -> regs (lane-private)
    f32x4 av[4][2][2];
    int koff = kt << 6;
#pragma unroll
    for (int m = 0; m < 4; ++m)
#pragma unroll
      for (int kk = 0; kk < 2; ++kk) {
        const float* p = ap[m] + koff + (kk << 5);
        av[m][kk][0] = *(const f32x4*)p;
        av[m][kk][1] = *(const f32x4*)(p + 4);
      }
    // drain: A(t) in regs; B(t+1) landed; B(t) was drained last iter
    asm volatile("s_waitcnt vmcnt(0)" ::: "memory");
    __builtin_amdgcn_sched_barrier(0);
    __syncthreads();
    const char* lb = &ldsB[kt & 1][0];
#pragma unroll
    for (int kk = 0; kk < 2; ++kk) {
      short8 af[4], bfr[4];
#pragma unroll
      for (int m = 0; m < 4; ++m) {
        u32 p0 = cvtpk(av[m][kk][0][0], av[m][kk][0][1]);
        u32 p1 = cvtpk(av[m][kk][0][2], av[m][kk][0][3]);
        u32 p2 = cvtpk(av[m][kk][1][0], av[m][kk][1][1]);
        u32 p3 = cvtpk(av[m][kk][1][2], av[m][kk][1][3]);
        af[m] = __builtin_bit_cast(short8, make_uint4(p0, p1, p2, p3));
      }
#pragma unroll
      for (int n = 0; n < 4; ++n)
        bfr[n] = __builtin_bit_cast(short8,
                                    *(const uint4*)(lb + (br_addr[n] ^ (kk << 6))));
#pragma unroll
      for (int m = 0; m < 4; ++m)
#pragma unroll
        for (int n = 0; n < 4; ++n)
          acc[m][n] = __builtin_amdgcn_mfma_f32_16x16x32_bf16(af[m], bfr[n],
                                                              acc[m][n], 0, 0, 0);
    }
  }

  // epilogue: C row = (lane>>4)*4 + reg, col = lane&15 (m89 layout)
  float bv[4];
#pragma unroll
  for (int n = 0; n < 4; ++n)
    bv[n] = bias[(e << 10) + n0 + (wc << 6) + (n << 4) + l15];
  int rq = (lane >> 4) << 2;
#pragma unroll
  for (int m = 0; m < 4; ++m) {
#pragma unroll
    for (int j = 0; j < 4; ++j) {
      int rl = (wr << 6) + (m << 4) + rq + j;
      if (rl < rim) {
        int grow = perm[row_base + rl];
        float* orow = out + (size_t)grow * NDIM + n0 + (wc << 6) + l15;
#pragma unroll
        for (int n = 0; n < 4; ++n) orow[n << 4] = acc[m][n][j] + bv[n];
      }
    }
  }
}

// ---------------- fallback (reg-staging, strided fp32 B) ----------------
__global__ __launch_bounds__(256, 3) void k_gemm_slow(
    const float* __restrict__ A, const float* __restrict__ W,
    const float* __restrict__ bias, const int* __restrict__ perm,
    const int* __restrict__ offsets, const int* __restrict__ counts,
    const int* __restrict__ tile_base, float* __restrict__ out) {
  int bid = blockIdx.x;
  const int cpx = GEMM_GRID >> 3;
  int l = (bid & 7) * cpx + (bid >> 3);
  int mt = l >> 3, nt = l & 7;
  if (mt >= tile_base[NE]) return;
  int e = 0;
#pragma unroll
  for (int ee = 0; ee < NE - 1; ++ee)
    if (mt >= tile_base[ee + 1]) e = ee + 1;
  int mloc = mt - tile_base[e];
  int row_base = offsets[e] + (mloc << 7);
  int rim = counts[e] - (mloc << 7);
  rim = rim < BM ? rim : BM;
  int n0 = nt << 7;

  __shared__ u16 Al[BM * 64];
  __shared__ u16 Bl[BN * 64];
  char* alb = (char*)Al;
  char* blb = (char*)Bl;

  int tid = threadIdx.x;
  int lane = tid & 63, wid = tid >> 6;
  int wr = wid >> 1, wc = wid & 1;
  int l15 = lane & 15;
  int lk2 = (lane >> 4) << 4;

  int acol4 = tid & 15, argp = tid >> 4;
  const float* arow_p[8];
  int aswz[8];
#pragma unroll
  for (int i = 0; i < 8; ++i) {
    int r = argp + (i << 4);
    int rr = r < rim ? r : rim - 1;
    int grow = perm[row_base + rr];
    arow_p[i] = A + (size_t)grow * KDIM + (acol4 << 2);
    aswz[i] = r * 128 + ((acol4 << 3) ^ swz_slot(r));
  }
  int bnloc = tid & 127;
  int bkh = tid >> 7;
  const float* bcol_f = W + ((size_t)e << 20) + n0 + bnloc;
  int bswz[4];
#pragma unroll
  for (int j = 0; j < 4; ++j)
    bswz[j] = bnloc * 128 + (((bkh << 6) + (j << 4)) ^ swz_slot(bnloc));

  int ar_addr[4], br_addr[4];
#pragma unroll
  for (int m = 0; m < 4; ++m) {
    int r = (wr << 6) + (m << 4) + l15;
    ar_addr[m] = r * 128 + (lk2 ^ swz_slot(r));
  }
#pragma unroll
  for (int n = 0; n < 4; ++n) {
    int r = (wc << 6) + (n << 4) + l15;
    br_addr[n] = r * 128 + (lk2 ^ swz_slot(r));
  }

  f32x4 acc[4][4];
#pragma unroll
  for (int m = 0; m < 4; ++m)
#pragma unroll
    for (int n = 0; n < 4; ++n) acc[m][n] = f32x4{0.f, 0.f, 0.f, 0.f};

#pragma unroll 1
  for (int kt = 0; kt < KDIM / 64; ++kt) {
    int k0 = kt << 6;
    __syncthreads();
#pragma unroll
    for (int i = 0; i < 8; ++i) {
      float4 v = *(const float4*)(arow_p[i] + k0);
      u32 lo = (u32)f2bf(v.x) | ((u32)f2bf(v.y) << 16);
      u32 hi = (u32)f2bf(v.z) | ((u32)f2bf(v.w) << 16);
      *(uint2*)(alb + aswz[i]) = make_uint2(lo, hi);
    }
    float vv[32];
#pragma unroll
    for (int i = 0; i < 32; ++i)
      vv[i] = bcol_f[(size_t)(k0 + (bkh << 5) + i) << 10];
#pragma unroll
    for (int j = 0; j < 4; ++j) {
      uint4 pkt;
      pkt.x = (u32)f2bf(vv[j * 8 + 0]) | ((u32)f2bf(vv[j * 8 + 1]) << 16);
      pkt.y = (u32)f2bf(vv[j * 8 + 2]) | ((u32)f2bf(vv[j * 8 + 3]) << 16);
      pkt.z = (u32)f2bf(vv[j * 8 + 4]) | ((u32)f2bf(vv[j * 8 + 5]) << 16);
      pkt.w = (u32)f2bf(vv[j * 8 + 6]) | ((u32)f2bf(vv[j * 8 + 7]) << 16);
      *(uint4*)(blb + bswz[j]) = pkt;
    }
    __syncthreads();
#pragma unroll
    for (int kk = 0; kk < 2; ++kk) {
      int kx = kk << 6;
      short8 af[4], bfr[4];
#pragma unroll
      for (int m = 0; m < 4; ++m)
        af[m] = __builtin_bit_cast(short8, *(const uint4*)(alb + (ar_addr[m] ^ kx)));
#pragma unroll
      for (int n = 0; n < 4; ++n)
        bfr[n] = __builtin_bit_cast(short8, *(const uint4*)(blb + (br_addr[n] ^ kx)));
#pragma unroll
      for (int m = 0; m < 4; ++m)
#pragma unroll
        for (int n = 0; n < 4; ++n)
          acc[m][n] = __builtin_amdgcn_mfma_f32_16x16x32_bf16(af[m], bfr[n],
                                                              acc[m][n], 0, 0, 0);
    }
  }

  float bv[4];
#pragma unroll
  for (int n = 0; n < 4; ++n)
    bv[n] = bias[(e << 10) + n0 + (wc << 6) + (n << 4) + l15];
  int rq = (lane >> 4) << 2;
#pragma unroll
  for (int m = 0; m < 4; ++m) {
#pragma unroll
    for (int j = 0; j < 4; ++j) {
      int rl = (wr << 6) + (m << 4) + rq + j;
      if (rl < rim) {
        int grow = perm[row_base + rl];
        float* orow = out + (size_t)grow * NDIM + n0 + (wc << 6) + l15;
#pragma unroll
        for (int n = 0; n < 4; ++n) orow[n << 4] = acc[m][n][j] + bv[n];
      }
    }
  }
}

extern "C" void kernel_launch(void* const* d_in, const int* in_sizes, int n_in,
                              void* d_out, int out_size, void* d_ws,
                              size_t ws_size, hipStream_t stream) {
  const float* A = (const float*)d_in[0];
  const int* ids = (const int*)d_in[1];
  const float* W = (const float*)d_in[2];
  const float* bias = (const float*)d_in[3];
  float* out = (float*)d_out;

  char* ws = (char*)d_ws;
  int* counts = (int*)ws;            // ws+0    : 8
  int* offsets = (int*)(ws + 32);    // ws+32   : 8
  int* tile_base = (int*)(ws + 64);  // ws+64   : 9
  int* gcnt = (int*)(ws + 128);      // ws+128  : 512
  int* base = (int*)(ws + 2176);     // ws+2176 : 512
  int* perm = (int*)(ws + 8192);     // ws+8192 : 65536 ints
  const size_t wt_off = 524288;
  const size_t wt_sz = (size_t)NE * 8 * 16 * TILE_B;  // 16,777,216
  u16* Wt = (u16*)(ws + wt_off);
  bool fast = ws_size >= wt_off + wt_sz;

  k_cnt<<<SORT_BLOCKS, 256, 0, stream>>>(ids, gcnt);
  k_excl<<<1, 64, 0, stream>>>(gcnt, counts, offsets, tile_base, base);
  k_place<<<SORT_BLOCKS, 256, 0, stream>>>(ids, base, perm);
  if (fast) {
    k_wconv2<<<NE * 8 * 16, 256, 0, stream>>>(W, Wt);
    k_gemm_fused<<<GEMM_GRID, 256, 0, stream>>>(A, Wt, bias, perm, offsets,
                                                counts, tile_base, out);
  } else {
    k_gemm_slow<<<GEMM_GRID, 256, 0, stream>>>(A, W, bias, perm, offsets,
                                               counts, tile_base, out);
  }
}

// Round 7
// 548.118 us; speedup vs baseline: 1.0811x; 1.0811x over previous
//
#include <hip/hip_runtime.h>

typedef unsigned short u16;
typedef unsigned int u32;
typedef __attribute__((ext_vector_type(8))) short short8;
typedef __attribute__((ext_vector_type(4))) float f32x4;

#define NF 65536
#define KDIM 1024
#define NDIM 1024
#define NE 8
#define BM 128
#define BN 128
#define MAX_MT (NF / BM + NE)   // 520 upper bound on total m-tiles
#define GEMM_GRID (MAX_MT * 8)  // 4160, divisible by 8 (XCD swizzle valid)
#define TILE_B 16384            // one 128x64 bf16 tile = LDS image bytes
#define SORT_BLOCKS 64

#define AS1 __attribute__((address_space(1)))
#define AS3 __attribute__((address_space(3)))

__device__ __forceinline__ u16 f2bf(float f) {
  u32 u = __float_as_uint(f);
  u += 0x7FFF + ((u >> 16) & 1);  // RNE (no NaN in this data)
  return (u16)(u >> 16);
}

// 3-bit slot swizzle
__device__ __forceinline__ int swz8(int r) {
  return (r & 7) ^ ((r >> 3) & 7);
}
__device__ __forceinline__ int swz_slot(int r) { return swz8(r) << 4; }

__device__ __forceinline__ void cp16(void* l, const void* g) {
  __builtin_amdgcn_global_load_lds((const AS1 unsigned int*)g,
                                   (AS3 unsigned int*)l, 16, 0, 0);
}

// pack two f32 -> two bf16 (RNE) in one VALU op
__device__ __forceinline__ u32 cvtpk(float a, float b) {
  u32 r;
  asm("v_cvt_pk_bf16_f32 %0, %1, %2" : "=v"(r) : "v"(a), "v"(b));
  return r;
}

// ---------- deterministic (atomic-free) counting sort ----------
__global__ void k_cnt(const int* __restrict__ ids, int* __restrict__ gcnt) {
  __shared__ int wc[16][NE];
  int b = blockIdx.x, t = threadIdx.x;
  int w = t >> 6, lane = t & 63;
  if (t < 16 * NE) ((int*)wc)[t] = 0;
  __syncthreads();
  for (int s = 0; s < 4; ++s) {
    int i = (b << 10) + (s << 8) + t;
    int e = ids[i];
#pragma unroll
    for (int ee = 0; ee < NE; ++ee) {
      unsigned long long mask = __ballot(e == ee);
      if (lane == 0) wc[(s << 2) + w][ee] = (int)__popcll(mask);
    }
  }
  __syncthreads();
  if (t < NE) {
    int sum = 0;
#pragma unroll
    for (int j = 0; j < 16; ++j) sum += wc[j][t];
    gcnt[b * NE + t] = sum;
  }
}

__global__ void k_excl(const int* __restrict__ gcnt, int* __restrict__ counts,
                       int* __restrict__ offsets, int* __restrict__ tile_base,
                       int* __restrict__ base) {
  __shared__ int tot[NE], offs[NE];
  int t = threadIdx.x;
  if (t < NE) {
    int s = 0;
    for (int b = 0; b < SORT_BLOCKS; ++b) s += gcnt[b * NE + t];
    tot[t] = s;
    counts[t] = s;
  }
  __syncthreads();
  if (t == 0) {
    int run = 0, tb = 0;
    tile_base[0] = 0;
    for (int e = 0; e < NE; ++e) {
      offsets[e] = run;
      offs[e] = run;
      run += tot[e];
      tb += (tot[e] + BM - 1) / BM;
      tile_base[e + 1] = tb;
    }
  }
  __syncthreads();
  if (t < NE) {
    int run = offs[t];
    for (int b = 0; b < SORT_BLOCKS; ++b) {
      base[b * NE + t] = run;
      run += gcnt[b * NE + t];
    }
  }
}

__global__ void k_place(const int* __restrict__ ids, const int* __restrict__ base,
                        int* __restrict__ perm) {
  __shared__ int wc[16][NE], wsc[16][NE];
  int b = blockIdx.x, t = threadIdx.x;
  int w = t >> 6, lane = t & 63;
  for (int s = 0; s < 4; ++s) {
    int i = (b << 10) + (s << 8) + t;
    int e = ids[i];
#pragma unroll
    for (int ee = 0; ee < NE; ++ee) {
      unsigned long long mask = __ballot(e == ee);
      if (lane == 0) wc[(s << 2) + w][ee] = (int)__popcll(mask);
    }
  }
  __syncthreads();
  if (t < NE) {
    int run = 0;
#pragma unroll
    for (int j = 0; j < 16; ++j) {
      wsc[j][t] = run;
      run += wc[j][t];
    }
  }
  __syncthreads();
  for (int s = 0; s < 4; ++s) {
    int i = (b << 10) + (s << 8) + t;
    int e = ids[i];
#pragma unroll
    for (int ee = 0; ee < NE; ++ee) {
      unsigned long long mask = __ballot(e == ee);
      if (e == ee) {
        int rank = (int)__popcll(mask & ((1ull << lane) - 1ull));
        perm[base[b * NE + e] + wsc[(s << 2) + w][e] + rank] = i;
      }
    }
  }
}

// ---------- A fp32 -> bf16, linear streaming (no gather) ----------
__global__ void k_abf(const float* __restrict__ A, u16* __restrict__ Ab) {
  int t = blockIdx.x * blockDim.x + threadIdx.x;
  int stride = gridDim.x * blockDim.x;
  const float4* src = (const float4*)A;
  uint4* dst = (uint4*)Ab;
  const int n = NF * (KDIM / 8);  // 8M uint4 outputs
  for (int i = t; i < n; i += stride) {
    float4 v0 = src[2 * i];
    float4 v1 = src[2 * i + 1];
    dst[i] = make_uint4(cvtpk(v0.x, v0.y), cvtpk(v0.z, v0.w),
                        cvtpk(v1.x, v1.y), cvtpk(v1.z, v1.w));
  }
}

// W[e][k][n] fp32 -> bf16 tiles [e][nt][kt][swizzled 128x64 image]
__global__ void k_wconv2(const float* __restrict__ W, u16* __restrict__ Wt) {
  int b = blockIdx.x;  // 8*8*16 = 1024 : b = (e*8+nt)*16+kt
  int e = b >> 7, nt = (b >> 4) & 7, kt = b & 15;
  int tid = threadIdx.x;
  const float* We = W + ((size_t)e << 20);
  char* dst = (char*)Wt + (size_t)b * TILE_B;
#pragma unroll
  for (int i = 0; i < 4; ++i) {
    int o = (i << 12) + (tid << 4);
    int r = o >> 7;
    int s = ((o >> 4) & 7) ^ swz8(r);
    int n = (nt << 7) + r;
    int k = (kt << 6) + (s << 3);
    u32 p[4];
#pragma unroll
    for (int j = 0; j < 4; ++j) {
      u32 lo = f2bf(We[(size_t)(k + 2 * j) * NDIM + n]);
      u32 hi = f2bf(We[(size_t)(k + 2 * j + 1) * NDIM + n]);
      p[j] = lo | (hi << 16);
    }
    *(uint4*)(dst + o) = make_uint4(p[0], p[1], p[2], p[3]);
  }
}

// ---------- grouped GEMM: A bf16 global->reg (dbuf), B LDS (dbuf) ----------
// Per K-step: issue A(t+1) frag loads (8x dwordx4, lane-private) + B(t+1)
// global_load_lds (4x), then vmcnt(12) keeps exactly those 12 in flight while
// draining A(t)/B(t). Two barriers/step (staging-ready; WAR on B buffers).
__global__ __launch_bounds__(256, 3) void k_gemm_areg(
    const u16* __restrict__ Ab, const u16* __restrict__ Wt,
    const float* __restrict__ bias, const int* __restrict__ perm,
    const int* __restrict__ offsets, const int* __restrict__ counts,
    const int* __restrict__ tile_base, float* __restrict__ out) {
  int bid = blockIdx.x;
  const int cpx = GEMM_GRID >> 3;
  int l = (bid & 7) * cpx + (bid >> 3);  // XCD swizzle
  int mt = l >> 3, nt = l & 7;           // n fastest: A-panel L2 reuse
  if (mt >= tile_base[NE]) return;
  int e = 0;
#pragma unroll
  for (int ee = 0; ee < NE - 1; ++ee)
    if (mt >= tile_base[ee + 1]) e = ee + 1;
  int mloc = mt - tile_base[e];
  int row_base = offsets[e] + (mloc << 7);
  int rim = counts[e] - (mloc << 7);
  rim = rim < BM ? rim : BM;
  int n0 = nt << 7;

  __shared__ __align__(16) char ldsB[2][TILE_B];  // 32 KB

  int tid = threadIdx.x;
  int lane = tid & 63, wid = tid >> 6;
  int wr = wid >> 1, wc = wid & 1;
  int l15 = lane & 15;
  int q4 = lane >> 4;
  int lk2 = q4 << 4;

  // ---- A frag base byte-offsets (lane-private rows; q4 selects 16B k-chunk)
  const char* AbB = (const char*)Ab;
  u32 abase[4];
#pragma unroll
  for (int m = 0; m < 4; ++m) {
    int r = (wr << 6) + (m << 4) + l15;
    int rr = r < rim ? r : rim - 1;  // dup row for pad (dead rows discarded)
    u32 g = (u32)perm[row_base + rr];
    abase[m] = (g << 11) + ((u32)q4 << 4);
  }

  // ---- B staging: Wt tile byte order == LDS image; 4 issues x 4KB strided.
  const char* srcB = (const char*)Wt + (size_t)(((e << 3) + nt) << 4) * TILE_B;
  int toff = tid << 4;

  // ---- B frag read addresses (kk -> ^64)
  int br_addr[4];
#pragma unroll
  for (int n = 0; n < 4; ++n) {
    int r = (wc << 6) + (n << 4) + l15;
    br_addr[n] = (r << 7) + (lk2 ^ swz_slot(r));
  }

  f32x4 acc[4][4];
#pragma unroll
  for (int m = 0; m < 4; ++m)
#pragma unroll
    for (int n = 0; n < 4; ++n) acc[m][n] = f32x4{0.f, 0.f, 0.f, 0.f};

  short8 afA[4][2], afB[4][2];

  // ---- prologue: A(0) -> afA (8 loads), B(0) -> buf0 (4 cp16)
#pragma unroll
  for (int m = 0; m < 4; ++m) {
    afA[m][0] = *(const short8*)(AbB + abase[m]);
    afA[m][1] = *(const short8*)(AbB + (abase[m] + 64));
  }
#pragma unroll
  for (int j = 0; j < 4; ++j)
    cp16(&ldsB[0][0] + toff + (j << 12), srcB + toff + (j << 12));

  auto STEP = [&](short8(&cur)[4][2], short8(&nxt)[4][2], int t) {
    int tn = t + 1 < 16 ? t + 1 : 15;  // clamp: dup A prefetch on last iter
    u32 kb = (u32)tn << 7;             // 128 bytes per K-step
#pragma unroll
    for (int m = 0; m < 4; ++m) {
      nxt[m][0] = *(const short8*)(AbB + (abase[m] + kb));
      nxt[m][1] = *(const short8*)(AbB + (abase[m] + kb + 64));
    }
    if (t + 1 < 16) {
      const char* gb = srcB + ((size_t)(t + 1) << 14);
      char* lbw = &ldsB[(t + 1) & 1][0];
#pragma unroll
      for (int j = 0; j < 4; ++j)
        cp16(lbw + toff + (j << 12), gb + toff + (j << 12));
    }
    // Keep the 12 just-issued prefetch ops in flight; drain A(t), B(t).
    asm volatile("s_waitcnt vmcnt(12)" ::: "memory");
    __builtin_amdgcn_sched_barrier(0);
    __syncthreads();  // all waves' B(t) staged
    const char* lb = &ldsB[t & 1][0];
#pragma unroll
    for (int kk = 0; kk < 2; ++kk) {
      short8 bfr[4];
#pragma unroll
      for (int n = 0; n < 4; ++n)
        bfr[n] = *(const short8*)(lb + (br_addr[n] ^ (kk << 6)));
#pragma unroll
      for (int m = 0; m < 4; ++m)
#pragma unroll
        for (int n = 0; n < 4; ++n)
          acc[m][n] = __builtin_amdgcn_mfma_f32_16x16x32_bf16(cur[m][kk], bfr[n],
                                                              acc[m][n], 0, 0, 0);
    }
    __syncthreads();  // readers done before next step's staging overwrites
  };

#pragma unroll 1
  for (int t = 0; t < 16; t += 2) {
    STEP(afA, afB, t);
    STEP(afB, afA, t + 1);
  }

  // epilogue: C row = (lane>>4)*4 + reg, col = lane&15 (m89 layout)
  float bv[4];
#pragma unroll
  for (int n = 0; n < 4; ++n)
    bv[n] = bias[(e << 10) + n0 + (wc << 6) + (n << 4) + l15];
  int rq = (lane >> 4) << 2;
#pragma unroll
  for (int m = 0; m < 4; ++m) {
#pragma unroll
    for (int j = 0; j < 4; ++j) {
      int rl = (wr << 6) + (m << 4) + rq + j;
      if (rl < rim) {
        int grow = perm[row_base + rl];
        float* orow = out + (size_t)grow * NDIM + n0 + (wc << 6) + l15;
#pragma unroll
        for (int n = 0; n < 4; ++n) orow[n << 4] = acc[m][n][j] + bv[n];
      }
    }
  }
}

// ---------------- fallback (reg-staging, strided fp32 B) ----------------
__global__ __launch_bounds__(256, 3) void k_gemm_slow(
    const float* __restrict__ A, const float* __restrict__ W,
    const float* __restrict__ bias, const int* __restrict__ perm,
    const int* __restrict__ offsets, const int* __restrict__ counts,
    const int* __restrict__ tile_base, float* __restrict__ out) {
  int bid = blockIdx.x;
  const int cpx = GEMM_GRID >> 3;
  int l = (bid & 7) * cpx + (bid >> 3);
  int mt = l >> 3, nt = l & 7;
  if (mt >= tile_base[NE]) return;
  int e = 0;
#pragma unroll
  for (int ee = 0; ee < NE - 1; ++ee)
    if (mt >= tile_base[ee + 1]) e = ee + 1;
  int mloc = mt - tile_base[e];
  int row_base = offsets[e] + (mloc << 7);
  int rim = counts[e] - (mloc << 7);
  rim = rim < BM ? rim : BM;
  int n0 = nt << 7;

  __shared__ u16 Al[BM * 64];
  __shared__ u16 Bl[BN * 64];
  char* alb = (char*)Al;
  char* blb = (char*)Bl;

  int tid = threadIdx.x;
  int lane = tid & 63, wid = tid >> 6;
  int wr = wid >> 1, wc = wid & 1;
  int l15 = lane & 15;
  int lk2 = (lane >> 4) << 4;

  int acol4 = tid & 15, argp = tid >> 4;
  const float* arow_p[8];
  int aswz[8];
#pragma unroll
  for (int i = 0; i < 8; ++i) {
    int r = argp + (i << 4);
    int rr = r < rim ? r : rim - 1;
    int grow = perm[row_base + rr];
    arow_p[i] = A + (size_t)grow * KDIM + (acol4 << 2);
    aswz[i] = r * 128 + ((acol4 << 3) ^ swz_slot(r));
  }
  int bnloc = tid & 127;
  int bkh = tid >> 7;
  const float* bcol_f = W + ((size_t)e << 20) + n0 + bnloc;
  int bswz[4];
#pragma unroll
  for (int j = 0; j < 4; ++j)
    bswz[j] = bnloc * 128 + (((bkh << 6) + (j << 4)) ^ swz_slot(bnloc));

  int ar_addr[4], br_addr[4];
#pragma unroll
  for (int m = 0; m < 4; ++m) {
    int r = (wr << 6) + (m << 4) + l15;
    ar_addr[m] = r * 128 + (lk2 ^ swz_slot(r));
  }
#pragma unroll
  for (int n = 0; n < 4; ++n) {
    int r = (wc << 6) + (n << 4) + l15;
    br_addr[n] = r * 128 + (lk2 ^ swz_slot(r));
  }

  f32x4 acc[4][4];
#pragma unroll
  for (int m = 0; m < 4; ++m)
#pragma unroll
    for (int n = 0; n < 4; ++n) acc[m][n] = f32x4{0.f, 0.f, 0.f, 0.f};

#pragma unroll 1
  for (int kt = 0; kt < KDIM / 64; ++kt) {
    int k0 = kt << 6;
    __syncthreads();
#pragma unroll
    for (int i = 0; i < 8; ++i) {
      float4 v = *(const float4*)(arow_p[i] + k0);
      u32 lo = (u32)f2bf(v.x) | ((u32)f2bf(v.y) << 16);
      u32 hi = (u32)f2bf(v.z) | ((u32)f2bf(v.w) << 16);
      *(uint2*)(alb + aswz[i]) = make_uint2(lo, hi);
    }
    float vv[32];
#pragma unroll
    for (int i = 0; i < 32; ++i)
      vv[i] = bcol_f[(size_t)(k0 + (bkh << 5) + i) << 10];
#pragma unroll
    for (int j = 0; j < 4; ++j) {
      uint4 pkt;
      pkt.x = (u32)f2bf(vv[j * 8 + 0]) | ((u32)f2bf(vv[j * 8 + 1]) << 16);
      pkt.y = (u32)f2bf(vv[j * 8 + 2]) | ((u32)f2bf(vv[j * 8 + 3]) << 16);
      pkt.z = (u32)f2bf(vv[j * 8 + 4]) | ((u32)f2bf(vv[j * 8 + 5]) << 16);
      pkt.w = (u32)f2bf(vv[j * 8 + 6]) | ((u32)f2bf(vv[j * 8 + 7]) << 16);
      *(uint4*)(blb + bswz[j]) = pkt;
    }
    __syncthreads();
#pragma unroll
    for (int kk = 0; kk < 2; ++kk) {
      int kx = kk << 6;
      short8 af[4], bfr[4];
#pragma unroll
      for (int m = 0; m < 4; ++m)
        af[m] = __builtin_bit_cast(short8, *(const uint4*)(alb + (ar_addr[m] ^ kx)));
#pragma unroll
      for (int n = 0; n < 4; ++n)
        bfr[n] = __builtin_bit_cast(short8, *(const uint4*)(blb + (br_addr[n] ^ kx)));
#pragma unroll
      for (int m = 0; m < 4; ++m)
#pragma unroll
        for (int n = 0; n < 4; ++n)
          acc[m][n] = __builtin_amdgcn_mfma_f32_16x16x32_bf16(af[m], bfr[n],
                                                              acc[m][n], 0, 0, 0);
    }
  }

  float bv[4];
#pragma unroll
  for (int n = 0; n < 4; ++n)
    bv[n] = bias[(e << 10) + n0 + (wc << 6) + (n << 4) + l15];
  int rq = (lane >> 4) << 2;
#pragma unroll
  for (int m = 0; m < 4; ++m) {
#pragma unroll
    for (int j = 0; j < 4; ++j) {
      int rl = (wr << 6) + (m << 4) + rq + j;
      if (rl < rim) {
        int grow = perm[row_base + rl];
        float* orow = out + (size_t)grow * NDIM + n0 + (wc << 6) + l15;
#pragma unroll
        for (int n = 0; n < 4; ++n) orow[n << 4] = acc[m][n][j] + bv[n];
      }
    }
  }
}

extern "C" void kernel_launch(void* const* d_in, const int* in_sizes, int n_in,
                              void* d_out, int out_size, void* d_ws,
                              size_t ws_size, hipStream_t stream) {
  const float* A = (const float*)d_in[0];
  const int* ids = (const int*)d_in[1];
  const float* W = (const float*)d_in[2];
  const float* bias = (const float*)d_in[3];
  float* out = (float*)d_out;

  char* ws = (char*)d_ws;
  int* counts = (int*)ws;            // ws+0    : 8
  int* offsets = (int*)(ws + 32);    // ws+32   : 8
  int* tile_base = (int*)(ws + 64);  // ws+64   : 9
  int* gcnt = (int*)(ws + 128);      // ws+128  : 512
  int* base = (int*)(ws + 2176);     // ws+2176 : 512
  int* perm = (int*)(ws + 8192);     // ws+8192 : 65536 ints
  const size_t ab_off = 524288;
  const size_t ab_sz = (size_t)NF * KDIM * 2;  // 128 MB bf16 A
  const size_t wt_off = ab_off + ab_sz;
  const size_t wt_sz = (size_t)NE * 8 * 16 * TILE_B;  // 16 MB
  u16* Ab = (u16*)(ws + ab_off);
  u16* Wt = (u16*)(ws + wt_off);
  bool fast = ws_size >= wt_off + wt_sz;

  k_cnt<<<SORT_BLOCKS, 256, 0, stream>>>(ids, gcnt);
  k_excl<<<1, 64, 0, stream>>>(gcnt, counts, offsets, tile_base, base);
  k_place<<<SORT_BLOCKS, 256, 0, stream>>>(ids, base, perm);
  if (fast) {
    k_abf<<<2048, 256, 0, stream>>>(A, Ab);
    k_wconv2<<<NE * 8 * 16, 256, 0, stream>>>(W, Wt);
    k_gemm_areg<<<GEMM_GRID, 256, 0, stream>>>(Ab, Wt, bias, perm, offsets,
                                               counts, tile_base, out);
  } else {
    k_gemm_slow<<<GEMM_GRID, 256, 0, stream>>>(A, W, bias, perm, offsets,
                                               counts, tile_base, out);
  }
}

// Round 8
// 331.088 us; speedup vs baseline: 1.7897x; 1.6555x over previous
//
#include <hip/hip_runtime.h>

typedef unsigned short u16;
typedef unsigned int u32;
typedef __attribute__((ext_vector_type(8))) short short8;
typedef __attribute__((ext_vector_type(4))) float f32x4;

#define NF 65536
#define KDIM 1024
#define NDIM 1024
#define NE 8
#define BM 128
#define MAX_MT (NF / BM + NE)
#define GEMM_GRID (MAX_MT * 8)  // fallback grid
#define TILE_B 16384            // one 128x64 bf16 tile image
#define SORT_BLOCKS 64
#define MAX_ST 264              // super(256)-tiles upper bound
#define GRID8 (MAX_ST * 4)      // 1056, %8==0
#define LDSZ (5 * 32768)        // 160 KiB exactly

#define AS1 __attribute__((address_space(1)))
#define AS3 __attribute__((address_space(3)))

#define BAR __builtin_amdgcn_s_barrier()
#define WAITV4                                        \
  asm volatile("s_waitcnt vmcnt(4)" ::: "memory");    \
  __builtin_amdgcn_sched_barrier(0)
#define WAITL0                                        \
  asm volatile("s_waitcnt lgkmcnt(0)" ::: "memory");  \
  __builtin_amdgcn_sched_barrier(0)

__device__ __forceinline__ u16 f2bf(float f) {
  u32 u = __float_as_uint(f);
  u += 0x7FFF + ((u >> 16) & 1);
  return (u16)(u >> 16);
}
__device__ __forceinline__ int swz8(int r) { return (r & 7) ^ ((r >> 3) & 7); }
__device__ __forceinline__ int swz_slot(int r) { return swz8(r) << 4; }
__device__ __forceinline__ void cp16(void* l, const void* g) {
  __builtin_amdgcn_global_load_lds((const AS1 unsigned int*)g,
                                   (AS3 unsigned int*)l, 16, 0, 0);
}
__device__ __forceinline__ u32 cvtpk(float a, float b) {
  u32 r;
  asm("v_cvt_pk_bf16_f32 %0, %1, %2" : "=v"(r) : "v"(a), "v"(b));
  return r;
}

// ---------- deterministic (atomic-free) counting sort ----------
__global__ void k_cnt(const int* __restrict__ ids, int* __restrict__ gcnt) {
  __shared__ int wc[16][NE];
  int b = blockIdx.x, t = threadIdx.x;
  int w = t >> 6, lane = t & 63;
  if (t < 16 * NE) ((int*)wc)[t] = 0;
  __syncthreads();
  for (int s = 0; s < 4; ++s) {
    int i = (b << 10) + (s << 8) + t;
    int e = ids[i];
#pragma unroll
    for (int ee = 0; ee < NE; ++ee) {
      unsigned long long mask = __ballot(e == ee);
      if (lane == 0) wc[(s << 2) + w][ee] = (int)__popcll(mask);
    }
  }
  __syncthreads();
  if (t < NE) {
    int sum = 0;
#pragma unroll
    for (int j = 0; j < 16; ++j) sum += wc[j][t];
    gcnt[b * NE + t] = sum;
  }
}

__global__ void k_excl(const int* __restrict__ gcnt, int* __restrict__ counts,
                       int* __restrict__ offsets, int* __restrict__ tile_base,
                       int* __restrict__ stb, int* __restrict__ base) {
  __shared__ int tot[NE], offs[NE];
  int t = threadIdx.x;
  if (t < NE) {
    int s = 0;
    for (int b = 0; b < SORT_BLOCKS; ++b) s += gcnt[b * NE + t];
    tot[t] = s;
    counts[t] = s;
  }
  __syncthreads();
  if (t == 0) {
    int run = 0, tb = 0, sb = 0;
    tile_base[0] = 0;
    stb[0] = 0;
    for (int e = 0; e < NE; ++e) {
      offsets[e] = run;
      offs[e] = run;
      run += tot[e];
      tb += (tot[e] + BM - 1) / BM;
      tile_base[e + 1] = tb;
      sb += (tot[e] + 255) / 256;
      stb[e + 1] = sb;
    }
  }
  __syncthreads();
  if (t < NE) {
    int run = offs[t];
    for (int b = 0; b < SORT_BLOCKS; ++b) {
      base[b * NE + t] = run;
      run += gcnt[b * NE + t];
    }
  }
}

__global__ void k_place(const int* __restrict__ ids, const int* __restrict__ base,
                        int* __restrict__ perm) {
  __shared__ int wc[16][NE], wsc[16][NE];
  int b = blockIdx.x, t = threadIdx.x;
  int w = t >> 6, lane = t & 63;
  for (int s = 0; s < 4; ++s) {
    int i = (b << 10) + (s << 8) + t;
    int e = ids[i];
#pragma unroll
    for (int ee = 0; ee < NE; ++ee) {
      unsigned long long mask = __ballot(e == ee);
      if (lane == 0) wc[(s << 2) + w][ee] = (int)__popcll(mask);
    }
  }
  __syncthreads();
  if (t < NE) {
    int run = 0;
#pragma unroll
    for (int j = 0; j < 16; ++j) {
      wsc[j][t] = run;
      run += wc[j][t];
    }
  }
  __syncthreads();
  for (int s = 0; s < 4; ++s) {
    int i = (b << 10) + (s << 8) + t;
    int e = ids[i];
#pragma unroll
    for (int ee = 0; ee < NE; ++ee) {
      unsigned long long mask = __ballot(e == ee);
      if (e == ee) {
        int rank = (int)__popcll(mask & ((1ull << lane) - 1ull));
        perm[base[b * NE + e] + wsc[(s << 2) + w][e] + rank] = i;
      }
    }
  }
}

// ---------- A gather+convert into 128-row swizzled tile images ----------
// Image index a = 2*stb[e] + local128 (2 images per super-tile, zero-padded).
__global__ void k_aconv(const float* __restrict__ A, const int* __restrict__ perm,
                        const int* __restrict__ counts,
                        const int* __restrict__ offsets,
                        const int* __restrict__ stb, u16* __restrict__ Abf) {
  int b = blockIdx.x;  // 2*MAX_ST*16
  int a = b >> 4, kt = b & 15;
  if (a >= (stb[NE] << 1)) return;
  int e = 0;
#pragma unroll
  for (int ee = 0; ee < NE - 1; ++ee)
    if (a >= (stb[ee + 1] << 1)) e = ee + 1;
  int loc = a - (stb[e] << 1);
  int row_base = offsets[e] + (loc << 7);
  int rim = counts[e] - (loc << 7);
  rim = rim < BM ? rim : BM;  // may be <= 0 (pad image)
  int tid = threadIdx.x;
  char* dst = (char*)Abf + (size_t)(a * 16 + kt) * TILE_B;
#pragma unroll
  for (int i = 0; i < 4; ++i) {
    int o = (i << 12) + (tid << 4);
    int r = o >> 7;
    int s = ((o >> 4) & 7) ^ swz8(r);
    uint4 pkt = make_uint4(0, 0, 0, 0);
    if (r < rim) {
      int g = perm[row_base + r];
      const float* src = A + (size_t)g * KDIM + (kt << 6) + (s << 3);
      float4 v0 = ((const float4*)src)[0];
      float4 v1 = ((const float4*)src)[1];
      pkt.x = cvtpk(v0.x, v0.y);
      pkt.y = cvtpk(v0.z, v0.w);
      pkt.z = cvtpk(v1.x, v1.y);
      pkt.w = cvtpk(v1.z, v1.w);
    }
    *(uint4*)(dst + o) = pkt;
  }
}

// W[e][k][n] fp32 -> bf16 tiles [e][nt128][kt][swizzled 128x64 image]
__global__ void k_wconv2(const float* __restrict__ W, u16* __restrict__ Wt) {
  int b = blockIdx.x;  // (e*8+nt)*16+kt
  int e = b >> 7, nt = (b >> 4) & 7, kt = b & 15;
  int tid = threadIdx.x;
  const float* We = W + ((size_t)e << 20);
  char* dst = (char*)Wt + (size_t)b * TILE_B;
#pragma unroll
  for (int i = 0; i < 4; ++i) {
    int o = (i << 12) + (tid << 4);
    int r = o >> 7;
    int s = ((o >> 4) & 7) ^ swz8(r);
    int n = (nt << 7) + r;
    int k = (kt << 6) + (s << 3);
    u32 p[4];
#pragma unroll
    for (int j = 0; j < 4; ++j) {
      u32 lo = f2bf(We[(size_t)(k + 2 * j) * NDIM + n]);
      u32 hi = f2bf(We[(size_t)(k + 2 * j + 1) * NDIM + n]);
      p[j] = lo | (hi << 16);
    }
    *(uint4*)(dst + o) = make_uint4(p[0], p[1], p[2], p[3]);
  }
}

// ---------- 8-phase 256^2 grouped GEMM (T3+T4+T5 port) ----------
// 5-slot LDS ring of 32KB half-tiles {A-image, B-image}; per K-tile 4 phases;
// staging 3-4 halves ahead; vmcnt(4) once per K-tile (never 0).
__global__ __launch_bounds__(512, 2) void k_gemm_8p(
    const u16* __restrict__ Abf, const u16* __restrict__ Wt,
    const float* __restrict__ bias, const int* __restrict__ perm,
    const int* __restrict__ offsets, const int* __restrict__ counts,
    const int* __restrict__ stb, float* __restrict__ out) {
  extern __shared__ __align__(16) char lds[];
  int bid = blockIdx.x;
  int l = (bid & 7) * (GRID8 >> 3) + (bid >> 3);  // XCD swizzle
  int st = l >> 2, nt2 = l & 3;                   // n fastest
  if (st >= stb[NE]) return;
  int e = 0;
#pragma unroll
  for (int ee = 0; ee < NE - 1; ++ee)
    if (st >= stb[ee + 1]) e = ee + 1;
  int sloc = st - stb[e];
  int row_base = offsets[e] + (sloc << 8);
  int rim = counts[e] - (sloc << 8);
  rim = rim < 256 ? rim : 256;

  int tid = threadIdx.x;
  int lane = tid & 63, wid = tid >> 6;
  int wr = wid >> 2, wc = wid & 3, w2 = wc >> 1;
  int l15 = lane & 15, q4 = lane >> 4, lk2 = q4 << 4;
  int t16 = tid << 4;

  const char* Ab0 = (const char*)Abf + (size_t)((st << 1) + 0) * 16 * TILE_B;
  const char* Ab1 = (const char*)Abf + (size_t)((st << 1) + 1) * 16 * TILE_B;
  const char* Bb0 =
      (const char*)Wt + (size_t)(((e << 3) + (nt2 << 1) + 0) * 16) * TILE_B;
  const char* Bb1 =
      (const char*)Wt + (size_t)(((e << 3) + (nt2 << 1) + 1) * 16) * TILE_B;

  int arx[8], brx[4];
#pragma unroll
  for (int m = 0; m < 8; ++m) {
    int r = (m << 4) + l15;
    arx[m] = (r << 7) + (lk2 ^ swz_slot(r));
  }
#pragma unroll
  for (int n = 0; n < 4; ++n) {
    int r = ((wc & 1) << 6) + (n << 4) + l15;
    brx[n] = (r << 7) + (lk2 ^ swz_slot(r));
  }

  f32x4 acc[8][4];
#pragma unroll
  for (int m = 0; m < 8; ++m)
#pragma unroll
    for (int n = 0; n < 4; ++n) acc[m][n] = f32x4{0.f, 0.f, 0.f, 0.f};

  // ---- prologue: stage halves 0,1,2 into slots 0,1,2
  {
    const char* sa[3] = {Ab0, Ab1, Ab0 + TILE_B};
    const char* sb[3] = {Bb0, Bb1, Bb0 + TILE_B};
#pragma unroll
    for (int h = 0; h < 3; ++h) {
      char* d = lds + (h << 15);
#pragma unroll
      for (int j = 0; j < 2; ++j) {
        cp16(d + (j << 13) + t16, sa[h] + (j << 13) + t16);
        cp16(d + 16384 + (j << 13) + t16, sb[h] + (j << 13) + t16);
      }
    }
  }
  WAITV4;  // halves 0,1 landed; half 2 in flight
  BAR;

  int s0 = 0;  // (2t) % 5
#pragma unroll 1
  for (int t = 0; t < 16; ++t) {
    int sA = s0 + wr;
    sA = sA >= 5 ? sA - 5 : sA;
    int sB = s0 + w2;
    sB = sB >= 5 ? sB - 5 : sB;
    const char* pa = lds + (sA << 15);
    const char* pb = lds + (sB << 15) + 16384;
    int sx = s0 + 3;
    sx = sx >= 5 ? sx - 5 : sx;
    int sy = s0 + 4;
    sy = sy >= 5 ? sy - 5 : sy;
    char* dx = lds + (sx << 15);  // half 2t+3 = tile t+1, mh/nh=1
    char* dy = lds + (sy << 15);  // half 2t+4 = tile t+2, mh/nh=0
    size_t o1 = (size_t)(t + 1 < 16 ? t + 1 : 15) * TILE_B;
    size_t o2 = (size_t)(t + 2 < 16 ? t + 2 : 15) * TILE_B;
    const char* gA1 = Ab1 + o1;
    const char* gB1 = Bb1 + o1;
    const char* gA0 = Ab0 + o2;
    const char* gB0 = Bb0 + o2;
    short8 bfr[4];
    // ---- phase 0: kk=0, m 0-3 (+B reads)
    {
      short8 afr[4];
#pragma unroll
      for (int n = 0; n < 4; ++n) bfr[n] = *(const short8*)(pb + brx[n]);
#pragma unroll
      for (int i = 0; i < 4; ++i) afr[i] = *(const short8*)(pa + arx[i]);
      cp16(dx + t16, gA1 + t16);
      cp16(dx + 16384 + t16, gB1 + t16);
      BAR;
      WAITL0;
      __builtin_amdgcn_s_setprio(1);
#pragma unroll
      for (int i = 0; i < 4; ++i)
#pragma unroll
        for (int n = 0; n < 4; ++n)
          acc[i][n] = __builtin_amdgcn_mfma_f32_16x16x32_bf16(afr[i], bfr[n],
                                                              acc[i][n], 0, 0, 0);
      __builtin_amdgcn_s_setprio(0);
      BAR;
    }
    // ---- phase 1: kk=0, m 4-7
    {
      short8 afr[4];
#pragma unroll
      for (int i = 0; i < 4; ++i) afr[i] = *(const short8*)(pa + arx[4 + i]);
      cp16(dx + 8192 + t16, gA1 + 8192 + t16);
      cp16(dx + 16384 + 8192 + t16, gB1 + 8192 + t16);
      BAR;
      WAITL0;
      __builtin_amdgcn_s_setprio(1);
#pragma unroll
      for (int i = 0; i < 4; ++i)
#pragma unroll
        for (int n = 0; n < 4; ++n)
          acc[4 + i][n] = __builtin_amdgcn_mfma_f32_16x16x32_bf16(
              afr[i], bfr[n], acc[4 + i][n], 0, 0, 0);
      __builtin_amdgcn_s_setprio(0);
      BAR;
    }
    // ---- phase 2: kk=1, m 0-3 (+B reads)
    {
      short8 afr[4];
#pragma unroll
      for (int n = 0; n < 4; ++n)
        bfr[n] = *(const short8*)(pb + (brx[n] ^ 64));
#pragma unroll
      for (int i = 0; i < 4; ++i)
        afr[i] = *(const short8*)(pa + (arx[i] ^ 64));
      cp16(dy + t16, gA0 + t16);
      cp16(dy + 16384 + t16, gB0 + t16);
      BAR;
      WAITL0;
      __builtin_amdgcn_s_setprio(1);
#pragma unroll
      for (int i = 0; i < 4; ++i)
#pragma unroll
        for (int n = 0; n < 4; ++n)
          acc[i][n] = __builtin_amdgcn_mfma_f32_16x16x32_bf16(afr[i], bfr[n],
                                                              acc[i][n], 0, 0, 0);
      __builtin_amdgcn_s_setprio(0);
      BAR;
    }
    // ---- phase 3: kk=1, m 4-7; close tile with vmcnt(4)
    {
      short8 afr[4];
#pragma unroll
      for (int i = 0; i < 4; ++i)
        afr[i] = *(const short8*)(pa + (arx[4 + i] ^ 64));
      cp16(dy + 8192 + t16, gA0 + 8192 + t16);
      cp16(dy + 16384 + 8192 + t16, gB0 + 8192 + t16);
      BAR;
      WAITL0;
      __builtin_amdgcn_s_setprio(1);
#pragma unroll
      for (int i = 0; i < 4; ++i)
#pragma unroll
        for (int n = 0; n < 4; ++n)
          acc[4 + i][n] = __builtin_amdgcn_mfma_f32_16x16x32_bf16(
              afr[i], bfr[n], acc[4 + i][n], 0, 0, 0);
      __builtin_amdgcn_s_setprio(0);
      WAITV4;  // halves <= 2t+3 landed -> tile t+1 may read 2t+2, 2t+3
      BAR;
    }
    s0 += 2;
    s0 = s0 >= 5 ? s0 - 5 : s0;
  }

  // epilogue: C row = q4*4 + reg, col = l15 (m89 layout)
  float bv[4];
#pragma unroll
  for (int n = 0; n < 4; ++n)
    bv[n] = bias[(e << 10) + (nt2 << 8) + (wc << 6) + (n << 4) + l15];
  int rq = q4 << 2;
#pragma unroll
  for (int m = 0; m < 8; ++m) {
#pragma unroll
    for (int j = 0; j < 4; ++j) {
      int rl = (wr << 7) + (m << 4) + rq + j;
      if (rl < rim) {
        int grow = perm[row_base + rl];
        float* orow =
            out + (size_t)grow * NDIM + (nt2 << 8) + (wc << 6) + l15;
#pragma unroll
        for (int n = 0; n < 4; ++n) orow[n << 4] = acc[m][n][j] + bv[n];
      }
    }
  }
}

// ---------------- fallback (reg-staging, strided fp32 B) ----------------
__global__ __launch_bounds__(256, 3) void k_gemm_slow(
    const float* __restrict__ A, const float* __restrict__ W,
    const float* __restrict__ bias, const int* __restrict__ perm,
    const int* __restrict__ offsets, const int* __restrict__ counts,
    const int* __restrict__ tile_base, float* __restrict__ out) {
  int bid = blockIdx.x;
  const int cpx = GEMM_GRID >> 3;
  int l = (bid & 7) * cpx + (bid >> 3);
  int mt = l >> 3, nt = l & 7;
  if (mt >= tile_base[NE]) return;
  int e = 0;
#pragma unroll
  for (int ee = 0; ee < NE - 1; ++ee)
    if (mt >= tile_base[ee + 1]) e = ee + 1;
  int mloc = mt - tile_base[e];
  int row_base = offsets[e] + (mloc << 7);
  int rim = counts[e] - (mloc << 7);
  rim = rim < BM ? rim : BM;
  int n0 = nt << 7;

  __shared__ u16 Al[BM * 64];
  __shared__ u16 Bl[BM * 64];
  char* alb = (char*)Al;
  char* blb = (char*)Bl;

  int tid = threadIdx.x;
  int lane = tid & 63, wid = tid >> 6;
  int wr = wid >> 1, wcc = wid & 1;
  int l15 = lane & 15;
  int lk2 = (lane >> 4) << 4;

  int acol4 = tid & 15, argp = tid >> 4;
  const float* arow_p[8];
  int aswz[8];
#pragma unroll
  for (int i = 0; i < 8; ++i) {
    int r = argp + (i << 4);
    int rr = r < rim ? r : rim - 1;
    int grow = perm[row_base + rr];
    arow_p[i] = A + (size_t)grow * KDIM + (acol4 << 2);
    aswz[i] = r * 128 + ((acol4 << 3) ^ swz_slot(r));
  }
  int bnloc = tid & 127;
  int bkh = tid >> 7;
  const float* bcol_f = W + ((size_t)e << 20) + n0 + bnloc;
  int bswz[4];
#pragma unroll
  for (int j = 0; j < 4; ++j)
    bswz[j] = bnloc * 128 + (((bkh << 6) + (j << 4)) ^ swz_slot(bnloc));

  int ar_addr[4], br_addr[4];
#pragma unroll
  for (int m = 0; m < 4; ++m) {
    int r = (wr << 6) + (m << 4) + l15;
    ar_addr[m] = r * 128 + (lk2 ^ swz_slot(r));
  }
#pragma unroll
  for (int n = 0; n < 4; ++n) {
    int r = (wcc << 6) + (n << 4) + l15;
    br_addr[n] = r * 128 + (lk2 ^ swz_slot(r));
  }

  f32x4 acc[4][4];
#pragma unroll
  for (int m = 0; m < 4; ++m)
#pragma unroll
    for (int n = 0; n < 4; ++n) acc[m][n] = f32x4{0.f, 0.f, 0.f, 0.f};

#pragma unroll 1
  for (int kt = 0; kt < KDIM / 64; ++kt) {
    int k0 = kt << 6;
    __syncthreads();
#pragma unroll
    for (int i = 0; i < 8; ++i) {
      float4 v = *(const float4*)(arow_p[i] + k0);
      u32 lo = (u32)f2bf(v.x) | ((u32)f2bf(v.y) << 16);
      u32 hi = (u32)f2bf(v.z) | ((u32)f2bf(v.w) << 16);
      *(uint2*)(alb + aswz[i]) = make_uint2(lo, hi);
    }
    float vv[32];
#pragma unroll
    for (int i = 0; i < 32; ++i)
      vv[i] = bcol_f[(size_t)(k0 + (bkh << 5) + i) << 10];
#pragma unroll
    for (int j = 0; j < 4; ++j) {
      uint4 pkt;
      pkt.x = (u32)f2bf(vv[j * 8 + 0]) | ((u32)f2bf(vv[j * 8 + 1]) << 16);
      pkt.y = (u32)f2bf(vv[j * 8 + 2]) | ((u32)f2bf(vv[j * 8 + 3]) << 16);
      pkt.z = (u32)f2bf(vv[j * 8 + 4]) | ((u32)f2bf(vv[j * 8 + 5]) << 16);
      pkt.w = (u32)f2bf(vv[j * 8 + 6]) | ((u32)f2bf(vv[j * 8 + 7]) << 16);
      *(uint4*)(blb + bswz[j]) = pkt;
    }
    __syncthreads();
#pragma unroll
    for (int kk = 0; kk < 2; ++kk) {
      int kx = kk << 6;
      short8 af[4], bfr[4];
#pragma unroll
      for (int m = 0; m < 4; ++m)
        af[m] = __builtin_bit_cast(short8, *(const uint4*)(alb + (ar_addr[m] ^ kx)));
#pragma unroll
      for (int n = 0; n < 4; ++n)
        bfr[n] = __builtin_bit_cast(short8, *(const uint4*)(blb + (br_addr[n] ^ kx)));
#pragma unroll
      for (int m = 0; m < 4; ++m)
#pragma unroll
        for (int n = 0; n < 4; ++n)
          acc[m][n] = __builtin_amdgcn_mfma_f32_16x16x32_bf16(af[m], bfr[n],
                                                              acc[m][n], 0, 0, 0);
    }
  }

  float bv[4];
#pragma unroll
  for (int n = 0; n < 4; ++n)
    bv[n] = bias[(e << 10) + n0 + (wcc << 6) + (n << 4) + l15];
  int rq = (lane >> 4) << 2;
#pragma unroll
  for (int m = 0; m < 4; ++m) {
#pragma unroll
    for (int j = 0; j < 4; ++j) {
      int rl = (wr << 6) + (m << 4) + rq + j;
      if (rl < rim) {
        int grow = perm[row_base + rl];
        float* orow = out + (size_t)grow * NDIM + n0 + (wcc << 6) + l15;
#pragma unroll
        for (int n = 0; n < 4; ++n) orow[n << 4] = acc[m][n][j] + bv[n];
      }
    }
  }
}

extern "C" void kernel_launch(void* const* d_in, const int* in_sizes, int n_in,
                              void* d_out, int out_size, void* d_ws,
                              size_t ws_size, hipStream_t stream) {
  const float* A = (const float*)d_in[0];
  const int* ids = (const int*)d_in[1];
  const float* W = (const float*)d_in[2];
  const float* bias = (const float*)d_in[3];
  float* out = (float*)d_out;

  char* ws = (char*)d_ws;
  int* counts = (int*)ws;             // ws+0   : 8
  int* offsets = (int*)(ws + 32);     // ws+32  : 8
  int* tile_base = (int*)(ws + 64);   // ws+64  : 9
  int* stb = (int*)(ws + 112);        // ws+112 : 9
  int* gcnt = (int*)(ws + 160);       // 512
  int* base = (int*)(ws + 2208);      // 512
  int* perm = (int*)(ws + 8192);      // 65536 ints
  const size_t abf_off = 524288;
  const size_t abf_sz = (size_t)2 * MAX_ST * 16 * TILE_B;  // 138,412,032
  const size_t wt_off = abf_off + abf_sz;
  const size_t wt_sz = (size_t)NE * 8 * 16 * TILE_B;  // 16,777,216
  u16* Abf = (u16*)(ws + abf_off);
  u16* Wt = (u16*)(ws + wt_off);
  bool fast = ws_size >= wt_off + wt_sz;
  if (fast) {
    hipError_t err = hipFuncSetAttribute(
        (const void*)k_gemm_8p, hipFuncAttributeMaxDynamicSharedMemorySize,
        LDSZ);
    if (err != hipSuccess) fast = false;
  }

  k_cnt<<<SORT_BLOCKS, 256, 0, stream>>>(ids, gcnt);
  k_excl<<<1, 64, 0, stream>>>(gcnt, counts, offsets, tile_base, stb, base);
  k_place<<<SORT_BLOCKS, 256, 0, stream>>>(ids, base, perm);
  if (fast) {
    k_wconv2<<<NE * 8 * 16, 256, 0, stream>>>(W, Wt);
    k_aconv<<<2 * MAX_ST * 16, 256, 0, stream>>>(A, perm, counts, offsets, stb,
                                                 Abf);
    k_gemm_8p<<<GRID8, 512, LDSZ, stream>>>(Abf, Wt, bias, perm, offsets,
                                            counts, stb, out);
  } else {
    k_gemm_slow<<<GEMM_GRID, 256, 0, stream>>>(A, W, bias, perm, offsets,
                                               counts, tile_base, out);
  }
}

// Round 9
// 297.728 us; speedup vs baseline: 1.9903x; 1.1120x over previous
//
#include <hip/hip_runtime.h>

typedef unsigned short u16;
typedef unsigned int u32;
typedef __attribute__((ext_vector_type(8))) short short8;
typedef __attribute__((ext_vector_type(4))) float f32x4;

#define NF 65536
#define KDIM 1024
#define NDIM 1024
#define NE 8
#define BM 128
#define BN 128
#define MAX_MT (NF / BM + NE)   // 520 upper bound on total m-tiles
#define GEMM_GRID (MAX_MT * 8)  // 4160, divisible by 8 (XCD swizzle valid)
#define TILE_B 16384            // one 128x64 bf16 tile = LDS image bytes
#define SORT_BLOCKS 64

#define AS1 __attribute__((address_space(1)))
#define AS3 __attribute__((address_space(3)))

__device__ __forceinline__ u16 f2bf(float f) {
  u32 u = __float_as_uint(f);
  u += 0x7FFF + ((u >> 16) & 1);  // RNE (no NaN in this data)
  return (u16)(u >> 16);
}

// 3-bit slot swizzle
__device__ __forceinline__ int swz8(int r) {
  return (r & 7) ^ ((r >> 3) & 7);
}
__device__ __forceinline__ int swz_slot(int r) { return swz8(r) << 4; }

__device__ __forceinline__ void cp16(void* l, const void* g) {
  __builtin_amdgcn_global_load_lds((const AS1 unsigned int*)g,
                                   (AS3 unsigned int*)l, 16, 0, 0);
}

// pack two f32 -> two bf16 (RNE) in one VALU op
__device__ __forceinline__ u32 cvtpk(float a, float b) {
  u32 r;
  asm("v_cvt_pk_bf16_f32 %0, %1, %2" : "=v"(r) : "v"(a), "v"(b));
  return r;
}

// ---------- deterministic (atomic-free) counting sort ----------
__global__ void k_cnt(const int* __restrict__ ids, int* __restrict__ gcnt) {
  __shared__ int wc[16][NE];
  int b = blockIdx.x, t = threadIdx.x;
  int w = t >> 6, lane = t & 63;
  if (t < 16 * NE) ((int*)wc)[t] = 0;
  __syncthreads();
  for (int s = 0; s < 4; ++s) {
    int i = (b << 10) + (s << 8) + t;
    int e = ids[i];
#pragma unroll
    for (int ee = 0; ee < NE; ++ee) {
      unsigned long long mask = __ballot(e == ee);
      if (lane == 0) wc[(s << 2) + w][ee] = (int)__popcll(mask);
    }
  }
  __syncthreads();
  if (t < NE) {
    int sum = 0;
#pragma unroll
    for (int j = 0; j < 16; ++j) sum += wc[j][t];
    gcnt[b * NE + t] = sum;
  }
}

__global__ void k_excl(const int* __restrict__ gcnt, int* __restrict__ counts,
                       int* __restrict__ offsets, int* __restrict__ tile_base,
                       int* __restrict__ base) {
  __shared__ int tot[NE], offs[NE];
  int t = threadIdx.x;
  if (t < NE) {
    int s = 0;
    for (int b = 0; b < SORT_BLOCKS; ++b) s += gcnt[b * NE + t];
    tot[t] = s;
    counts[t] = s;
  }
  __syncthreads();
  if (t == 0) {
    int run = 0, tb = 0;
    tile_base[0] = 0;
    for (int e = 0; e < NE; ++e) {
      offsets[e] = run;
      offs[e] = run;
      run += tot[e];
      tb += (tot[e] + BM - 1) / BM;
      tile_base[e + 1] = tb;
    }
  }
  __syncthreads();
  if (t < NE) {
    int run = offs[t];
    for (int b = 0; b < SORT_BLOCKS; ++b) {
      base[b * NE + t] = run;
      run += gcnt[b * NE + t];
    }
  }
}

__global__ void k_place(const int* __restrict__ ids, const int* __restrict__ base,
                        int* __restrict__ perm) {
  __shared__ int wc[16][NE], wsc[16][NE];
  int b = blockIdx.x, t = threadIdx.x;
  int w = t >> 6, lane = t & 63;
  for (int s = 0; s < 4; ++s) {
    int i = (b << 10) + (s << 8) + t;
    int e = ids[i];
#pragma unroll
    for (int ee = 0; ee < NE; ++ee) {
      unsigned long long mask = __ballot(e == ee);
      if (lane == 0) wc[(s << 2) + w][ee] = (int)__popcll(mask);
    }
  }
  __syncthreads();
  if (t < NE) {
    int run = 0;
#pragma unroll
    for (int j = 0; j < 16; ++j) {
      wsc[j][t] = run;
      run += wc[j][t];
    }
  }
  __syncthreads();
  for (int s = 0; s < 4; ++s) {
    int i = (b << 10) + (s << 8) + t;
    int e = ids[i];
#pragma unroll
    for (int ee = 0; ee < NE; ++ee) {
      unsigned long long mask = __ballot(e == ee);
      if (e == ee) {
        int rank = (int)__popcll(mask & ((1ull << lane) - 1ull));
        perm[base[b * NE + e] + wsc[(s << 2) + w][e] + rank] = i;
      }
    }
  }
}

// ---------- A fp32 -> bf16, pure linear streaming ----------
__global__ void k_abf(const float* __restrict__ A, u16* __restrict__ Ab) {
  int t = blockIdx.x * blockDim.x + threadIdx.x;
  int stride = gridDim.x * blockDim.x;
  const float4* src = (const float4*)A;
  uint4* dst = (uint4*)Ab;
  const int n = NF * (KDIM / 8);  // 8M uint4 outputs
  for (int i = t; i < n; i += stride) {
    float4 v0 = src[2 * i];
    float4 v1 = src[2 * i + 1];
    dst[i] = make_uint4(cvtpk(v0.x, v0.y), cvtpk(v0.z, v0.w),
                        cvtpk(v1.x, v1.y), cvtpk(v1.z, v1.w));
  }
}

// W[e][k][n] fp32 -> bf16 tiles [e][nt][kt][swizzled 128x64 image]
__global__ void k_wconv2(const float* __restrict__ W, u16* __restrict__ Wt) {
  int b = blockIdx.x;  // 8*8*16 = 1024 : b = (e*8+nt)*16+kt
  int e = b >> 7, nt = (b >> 4) & 7, kt = b & 15;
  int tid = threadIdx.x;
  const float* We = W + ((size_t)e << 20);
  char* dst = (char*)Wt + (size_t)b * TILE_B;
#pragma unroll
  for (int i = 0; i < 4; ++i) {
    int o = (i << 12) + (tid << 4);
    int r = o >> 7;
    int s = ((o >> 4) & 7) ^ swz8(r);
    int n = (nt << 7) + r;
    int k = (kt << 6) + (s << 3);
    u32 p[4];
#pragma unroll
    for (int j = 0; j < 4; ++j) {
      u32 lo = f2bf(We[(size_t)(k + 2 * j) * NDIM + n]);
      u32 hi = f2bf(We[(size_t)(k + 2 * j + 1) * NDIM + n]);
      p[j] = lo | (hi << 16);
    }
    *(uint4*)(dst + o) = make_uint4(p[0], p[1], p[2], p[3]);
  }
}

// ---------- grouped GEMM (R3 structure; A gathered at DMA time) ----------
// A staged via global_load_lds with PER-LANE gathered source from bf16 Ab:
// dest linear (o = j*4096 + tid*16), source row = perm[...o>>7], slot
// inverse-swizzled, so the LDS image is byte-identical to R3's Abf tile.
__global__ __launch_bounds__(256, 4) void k_gemm_gather(
    const u16* __restrict__ Ab, const u16* __restrict__ Wt,
    const float* __restrict__ bias, const int* __restrict__ perm,
    const int* __restrict__ offsets, const int* __restrict__ counts,
    const int* __restrict__ tile_base, float* __restrict__ out) {
  int bid = blockIdx.x;
  const int cpx = GEMM_GRID >> 3;
  int l = (bid & 7) * cpx + (bid >> 3);  // XCD swizzle
  int mt = l >> 3, nt = l & 7;           // n fastest: A-panel L2 reuse
  if (mt >= tile_base[NE]) return;
  int e = 0;
#pragma unroll
  for (int ee = 0; ee < NE - 1; ++ee)
    if (mt >= tile_base[ee + 1]) e = ee + 1;
  int mloc = mt - tile_base[e];
  int row_base = offsets[e] + (mloc << 7);
  int rim = counts[e] - (mloc << 7);
  rim = rim < BM ? rim : BM;
  int n0 = nt << 7;

  __shared__ __align__(16) char lds[2 * TILE_B];
  char* la = lds;
  char* lb = lds + TILE_B;

  int tid = threadIdx.x;
  int lane = tid & 63, wid = tid >> 6;
  int wr = wid >> 1, wc = wid & 1;
  int l15 = lane & 15;
  int lk2 = (lane >> 4) << 4;

  // ---- A gather source addresses (4 issues; row r = j*32 + tid>>3)
  const char* AbB = (const char*)Ab;
  u32 asrc[4];
#pragma unroll
  for (int j = 0; j < 4; ++j) {
    int o = (j << 12) + (tid << 4);
    int r = o >> 7;
    int s = ((o >> 4) & 7) ^ swz8(r);
    int rr = r < rim ? r : rim - 1;  // clamp: dup row, dead in epilogue
    u32 g = (u32)perm[row_base + rr];
    asrc[j] = (g << 11) + ((u32)s << 4);  // + kt*128 per K-step
  }

  const char* srcB = (const char*)Wt + (size_t)(((e << 3) + nt) << 4) * TILE_B;
  int toff = tid << 4;

  // ---- fragment read byte addresses (kk=0); kk=1 is addr ^ 64
  int ar_addr[4], br_addr[4];
#pragma unroll
  for (int m = 0; m < 4; ++m) {
    int r = (wr << 6) + (m << 4) + l15;
    ar_addr[m] = r * 128 + (lk2 ^ swz_slot(r));
  }
#pragma unroll
  for (int n = 0; n < 4; ++n) {
    int r = (wc << 6) + (n << 4) + l15;
    br_addr[n] = r * 128 + (lk2 ^ swz_slot(r));
  }

  f32x4 acc[4][4];
#pragma unroll
  for (int m = 0; m < 4; ++m)
#pragma unroll
    for (int n = 0; n < 4; ++n) acc[m][n] = f32x4{0.f, 0.f, 0.f, 0.f};

#pragma unroll 1
  for (int kt = 0; kt < KDIM / 64; ++kt) {
    __syncthreads();  // previous compute done; LDS reusable
    u32 kb = (u32)kt << 7;  // 128 B per K-step along a bf16 row
#pragma unroll
    for (int j = 0; j < 4; ++j)
      cp16(la + toff + (j << 12), AbB + (asrc[j] + kb));
    const char* gb = srcB + ((size_t)kt << 14);
#pragma unroll
    for (int j = 0; j < 4; ++j) cp16(lb + toff + (j << 12), gb + toff + (j << 12));
    asm volatile("s_waitcnt vmcnt(0)" ::: "memory");
    __builtin_amdgcn_sched_barrier(0);
    __syncthreads();
#pragma unroll
    for (int kk = 0; kk < 2; ++kk) {
      int kx = kk << 6;
      short8 af[4], bfr[4];
#pragma unroll
      for (int m = 0; m < 4; ++m)
        af[m] = __builtin_bit_cast(short8, *(const uint4*)(la + (ar_addr[m] ^ kx)));
#pragma unroll
      for (int n = 0; n < 4; ++n)
        bfr[n] = __builtin_bit_cast(short8, *(const uint4*)(lb + (br_addr[n] ^ kx)));
#pragma unroll
      for (int m = 0; m < 4; ++m)
#pragma unroll
        for (int n = 0; n < 4; ++n)
          acc[m][n] = __builtin_amdgcn_mfma_f32_16x16x32_bf16(af[m], bfr[n],
                                                              acc[m][n], 0, 0, 0);
    }
  }

  // epilogue: C row = (lane>>4)*4 + reg, col = lane&15 (m89 layout)
  float bv[4];
#pragma unroll
  for (int n = 0; n < 4; ++n)
    bv[n] = bias[(e << 10) + n0 + (wc << 6) + (n << 4) + l15];
  int rq = (lane >> 4) << 2;
#pragma unroll
  for (int m = 0; m < 4; ++m) {
#pragma unroll
    for (int j = 0; j < 4; ++j) {
      int rl = (wr << 6) + (m << 4) + rq + j;
      if (rl < rim) {
        int grow = perm[row_base + rl];
        float* orow = out + (size_t)grow * NDIM + n0 + (wc << 6) + l15;
#pragma unroll
        for (int n = 0; n < 4; ++n) orow[n << 4] = acc[m][n][j] + bv[n];
      }
    }
  }
}

// ---------------- fallback (reg-staging, strided fp32 B) ----------------
__global__ __launch_bounds__(256, 3) void k_gemm_slow(
    const float* __restrict__ A, const float* __restrict__ W,
    const float* __restrict__ bias, const int* __restrict__ perm,
    const int* __restrict__ offsets, const int* __restrict__ counts,
    const int* __restrict__ tile_base, float* __restrict__ out) {
  int bid = blockIdx.x;
  const int cpx = GEMM_GRID >> 3;
  int l = (bid & 7) * cpx + (bid >> 3);
  int mt = l >> 3, nt = l & 7;
  if (mt >= tile_base[NE]) return;
  int e = 0;
#pragma unroll
  for (int ee = 0; ee < NE - 1; ++ee)
    if (mt >= tile_base[ee + 1]) e = ee + 1;
  int mloc = mt - tile_base[e];
  int row_base = offsets[e] + (mloc << 7);
  int rim = counts[e] - (mloc << 7);
  rim = rim < BM ? rim : BM;
  int n0 = nt << 7;

  __shared__ u16 Al[BM * 64];
  __shared__ u16 Bl[BN * 64];
  char* alb = (char*)Al;
  char* blb = (char*)Bl;

  int tid = threadIdx.x;
  int lane = tid & 63, wid = tid >> 6;
  int wr = wid >> 1, wc = wid & 1;
  int l15 = lane & 15;
  int lk2 = (lane >> 4) << 4;

  int acol4 = tid & 15, argp = tid >> 4;
  const float* arow_p[8];
  int aswz[8];
#pragma unroll
  for (int i = 0; i < 8; ++i) {
    int r = argp + (i << 4);
    int rr = r < rim ? r : rim - 1;
    int grow = perm[row_base + rr];
    arow_p[i] = A + (size_t)grow * KDIM + (acol4 << 2);
    aswz[i] = r * 128 + ((acol4 << 3) ^ swz_slot(r));
  }
  int bnloc = tid & 127;
  int bkh = tid >> 7;
  const float* bcol_f = W + ((size_t)e << 20) + n0 + bnloc;
  int bswz[4];
#pragma unroll
  for (int j = 0; j < 4; ++j)
    bswz[j] = bnloc * 128 + (((bkh << 6) + (j << 4)) ^ swz_slot(bnloc));

  int ar_addr[4], br_addr[4];
#pragma unroll
  for (int m = 0; m < 4; ++m) {
    int r = (wr << 6) + (m << 4) + l15;
    ar_addr[m] = r * 128 + (lk2 ^ swz_slot(r));
  }
#pragma unroll
  for (int n = 0; n < 4; ++n) {
    int r = (wc << 6) + (n << 4) + l15;
    br_addr[n] = r * 128 + (lk2 ^ swz_slot(r));
  }

  f32x4 acc[4][4];
#pragma unroll
  for (int m = 0; m < 4; ++m)
#pragma unroll
    for (int n = 0; n < 4; ++n) acc[m][n] = f32x4{0.f, 0.f, 0.f, 0.f};

#pragma unroll 1
  for (int kt = 0; kt < KDIM / 64; ++kt) {
    int k0 = kt << 6;
    __syncthreads();
#pragma unroll
    for (int i = 0; i < 8; ++i) {
      float4 v = *(const float4*)(arow_p[i] + k0);
      u32 lo = (u32)f2bf(v.x) | ((u32)f2bf(v.y) << 16);
      u32 hi = (u32)f2bf(v.z) | ((u32)f2bf(v.w) << 16);
      *(uint2*)(alb + aswz[i]) = make_uint2(lo, hi);
    }
    float vv[32];
#pragma unroll
    for (int i = 0; i < 32; ++i)
      vv[i] = bcol_f[(size_t)(k0 + (bkh << 5) + i) << 10];
#pragma unroll
    for (int j = 0; j < 4; ++j) {
      uint4 pkt;
      pkt.x = (u32)f2bf(vv[j * 8 + 0]) | ((u32)f2bf(vv[j * 8 + 1]) << 16);
      pkt.y = (u32)f2bf(vv[j * 8 + 2]) | ((u32)f2bf(vv[j * 8 + 3]) << 16);
      pkt.z = (u32)f2bf(vv[j * 8 + 4]) | ((u32)f2bf(vv[j * 8 + 5]) << 16);
      pkt.w = (u32)f2bf(vv[j * 8 + 6]) | ((u32)f2bf(vv[j * 8 + 7]) << 16);
      *(uint4*)(blb + bswz[j]) = pkt;
    }
    __syncthreads();
#pragma unroll
    for (int kk = 0; kk < 2; ++kk) {
      int kx = kk << 6;
      short8 af[4], bfr[4];
#pragma unroll
      for (int m = 0; m < 4; ++m)
        af[m] = __builtin_bit_cast(short8, *(const uint4*)(alb + (ar_addr[m] ^ kx)));
#pragma unroll
      for (int n = 0; n < 4; ++n)
        bfr[n] = __builtin_bit_cast(short8, *(const uint4*)(blb + (br_addr[n] ^ kx)));
#pragma unroll
      for (int m = 0; m < 4; ++m)
#pragma unroll
        for (int n = 0; n < 4; ++n)
          acc[m][n] = __builtin_amdgcn_mfma_f32_16x16x32_bf16(af[m], bfr[n],
                                                              acc[m][n], 0, 0, 0);
    }
  }

  float bv[4];
#pragma unroll
  for (int n = 0; n < 4; ++n)
    bv[n] = bias[(e << 10) + n0 + (wc << 6) + (n << 4) + l15];
  int rq = (lane >> 4) << 2;
#pragma unroll
  for (int m = 0; m < 4; ++m) {
#pragma unroll
    for (int j = 0; j < 4; ++j) {
      int rl = (wr << 6) + (m << 4) + rq + j;
      if (rl < rim) {
        int grow = perm[row_base + rl];
        float* orow = out + (size_t)grow * NDIM + n0 + (wc << 6) + l15;
#pragma unroll
        for (int n = 0; n < 4; ++n) orow[n << 4] = acc[m][n][j] + bv[n];
      }
    }
  }
}

extern "C" void kernel_launch(void* const* d_in, const int* in_sizes, int n_in,
                              void* d_out, int out_size, void* d_ws,
                              size_t ws_size, hipStream_t stream) {
  const float* A = (const float*)d_in[0];
  const int* ids = (const int*)d_in[1];
  const float* W = (const float*)d_in[2];
  const float* bias = (const float*)d_in[3];
  float* out = (float*)d_out;

  char* ws = (char*)d_ws;
  int* counts = (int*)ws;            // ws+0    : 8
  int* offsets = (int*)(ws + 32);    // ws+32   : 8
  int* tile_base = (int*)(ws + 64);  // ws+64   : 9
  int* gcnt = (int*)(ws + 128);      // 512
  int* base = (int*)(ws + 2176);     // 512
  int* perm = (int*)(ws + 8192);     // 65536 ints
  const size_t ab_off = 524288;
  const size_t ab_sz = (size_t)NF * KDIM * 2;  // 128 MB bf16 A
  const size_t wt_off = ab_off + ab_sz;
  const size_t wt_sz = (size_t)NE * 8 * 16 * TILE_B;  // 16 MB
  u16* Ab = (u16*)(ws + ab_off);
  u16* Wt = (u16*)(ws + wt_off);
  bool fast = ws_size >= wt_off + wt_sz;

  k_cnt<<<SORT_BLOCKS, 256, 0, stream>>>(ids, gcnt);
  k_excl<<<1, 64, 0, stream>>>(gcnt, counts, offsets, tile_base, base);
  k_place<<<SORT_BLOCKS, 256, 0, stream>>>(ids, base, perm);
  if (fast) {
    k_abf<<<2048, 256, 0, stream>>>(A, Ab);
    k_wconv2<<<NE * 8 * 16, 256, 0, stream>>>(W, Wt);
    k_gemm_gather<<<GEMM_GRID, 256, 0, stream>>>(Ab, Wt, bias, perm, offsets,
                                                 counts, tile_base, out);
  } else {
    k_gemm_slow<<<GEMM_GRID, 256, 0, stream>>>(A, W, bias, perm, offsets,
                                               counts, tile_base, out);
  }
}